// Round 5
// baseline (678.142 us; speedup 1.0000x reference)
//
#include <hip/hip_runtime.h>
#include <hip/hip_bf16.h>
#include <cstdint>
#include <cstddef>

#define M_TOTAL 16384   // WORLD_SIZE * M_LOCAL
#define K_DIM   4096
#define N_DIM   4096

typedef __attribute__((ext_vector_type(8))) short s16x8;
typedef __attribute__((ext_vector_type(4))) float f32x4;
typedef unsigned short ushort_t;

// ---------- fp32 -> bf16 round-to-nearest-even ----------
__device__ __forceinline__ ushort_t f2bf(float x) {
  unsigned u = __float_as_uint(x);
  return (ushort_t)((u + 0x7fffu + ((u >> 16) & 1u)) >> 16);
}

// ---------- cast A [M,K] fp32 -> bf16, 8 elems/thread ----------
__global__ __launch_bounds__(256) void cast_kernel(const float* __restrict__ in,
                                                   ushort_t* __restrict__ out,
                                                   long n8) {
  long i = (long)blockIdx.x * 256 + threadIdx.x;
  if (i >= n8) return;
  const f32x4* p = (const f32x4*)in + i * 2;
  f32x4 a = p[0], b = p[1];
  union { s16x8 v; ushort_t u[8]; } r;
  r.u[0] = f2bf(a.x); r.u[1] = f2bf(a.y); r.u[2] = f2bf(a.z); r.u[3] = f2bf(a.w);
  r.u[4] = f2bf(b.x); r.u[5] = f2bf(b.y); r.u[6] = f2bf(b.z); r.u[7] = f2bf(b.w);
  *((s16x8*)out + i) = r.v;
}

// ---------- transpose+cast W [K,N] fp32 -> Bt [N,K] bf16 ----------
__global__ __launch_bounds__(256) void transpose_cast_kernel(const float* __restrict__ B,
                                                             ushort_t* __restrict__ Bt) {
  __shared__ float tile[64][65];
  int nbx = N_DIM / 64;
  int n0 = (blockIdx.x % nbx) * 64;
  int k0 = (blockIdx.x / nbx) * 64;
  int tx = threadIdx.x & 63;
  int ty = threadIdx.x >> 6;
#pragma unroll
  for (int i = 0; i < 64; i += 4)
    tile[ty + i][tx] = B[(size_t)(k0 + ty + i) * N_DIM + n0 + tx];
  __syncthreads();
#pragma unroll
  for (int i = 0; i < 64; i += 4)
    Bt[(size_t)(n0 + ty + i) * K_DIM + k0 + tx] = f2bf(tile[tx][ty + i]);
}

// ============================================================================
// 256x256 8-phase bf16 GEMM — round 5: R3 base (16x16x32, 0-conflict reads)
// with READS HOISTED ONE PHASE EARLY (before the preceding s_barrier fence):
//   P1: read A-q0 + B-n0 + B-n1 (16 b128);  P2: read A-q1 (8);  P3/P4: none.
// Compiler's fine-grained lgkmcnt then overlaps MFMA(P) with delivery of
// reads(P+1) — breaking the LDS<->MFMA per-phase ping-pong (52% MfmaUtil).
// Staging ledger / vmcnt / barriers / swizzle / epilogue IDENTICAL to R3:
//   P1: A(t1)h0->buf1 | P2: A(t1)h1 | P3: B(t2)h0->buf0 | P4: B(t2)h1,
//   [MFMA]; vmcnt(4) | P5-P8 mirror. WAR safety: B(t2)->buf0 staged at P3,
//   after P2's closing BAR which follows every wave's q01 MFMA (consumed n1).
// ============================================================================
#define BM 256
#define BN 256
#define BK 64
#define NTILE (K_DIM / BK)   // 64 -> 32 iterations, last peeled

__device__ __forceinline__ void load_lds16(const ushort_t* g, ushort_t* l) {
  __builtin_amdgcn_global_load_lds(
      (const __attribute__((address_space(1))) unsigned int*)g,
      (__attribute__((address_space(3))) unsigned int*)l, 16, 0, 0);
}

#define BAR __builtin_amdgcn_s_barrier()
#define VMW4 asm volatile("s_waitcnt vmcnt(4)" ::: "memory")
#define VMW0 asm volatile("s_waitcnt vmcnt(0)" ::: "memory")

#define STAGE_A(dst, h, t) do { \
    load_lds16(pA + (size_t)((h) * 128) * K_DIM + (t) * 64, (dst) + (h) * 8192); \
    load_lds16(pA + (size_t)((h) * 128 + 64) * K_DIM + (t) * 64, (dst) + (h) * 8192 + 4096); } while (0)
#define STAGE_B(dst, h, t) do { \
    load_lds16(pB + (size_t)((h) * 128) * K_DIM + (t) * 64, (dst) + (h) * 8192); \
    load_lds16(pB + (size_t)((h) * 128 + 64) * K_DIM + (t) * 64, (dst) + (h) * 8192 + 4096); } while (0)

#define READ_A(buf, arr, q) do { \
    _Pragma("unroll") for (int mf = 0; mf < 4; ++mf) { \
      int ia = aBase + ((q) * 4 + mf) * 1024; \
      arr[mf][0] = *(const s16x8*)&lds[buf][ia]; \
      arr[mf][1] = *(const s16x8*)&lds[buf][ia ^ 32]; } } while (0)
#define READ_B(buf, arr, nh) do { \
    _Pragma("unroll") for (int nf = 0; nf < 2; ++nf) { \
      int ib = bBase + ((nh) * 2 + nf) * 1024; \
      arr[nf][0] = *(const s16x8*)&lds[buf][ib]; \
      arr[nf][1] = *(const s16x8*)&lds[buf][ib ^ 32]; } } while (0)

// ks outermost: 8 independent MFMAs between accumulator reuse.
#define MFMA_Q(arr_a, arr_b, m0, n0) do { \
    __builtin_amdgcn_s_setprio(1); \
    _Pragma("unroll") for (int ks = 0; ks < 2; ++ks) \
    _Pragma("unroll") for (int mf = 0; mf < 4; ++mf) \
    _Pragma("unroll") for (int nf = 0; nf < 2; ++nf) \
      acc[(m0) + mf][(n0) + nf] = __builtin_amdgcn_mfma_f32_16x16x32_bf16( \
          arr_a[mf][ks], arr_b[nf][ks], acc[(m0) + mf][(n0) + nf], 0, 0, 0); \
    __builtin_amdgcn_s_setprio(0); } while (0)

__global__ __launch_bounds__(512, 2)
void gemm_8phase(const ushort_t* __restrict__ A, const ushort_t* __restrict__ Bt,
                 const float* __restrict__ bias, float* __restrict__ C) {
  __shared__ ushort_t lds[2][32768];  // [buf][ A: 0..16383 | B: 16384..32767 ]

  // bijective XCD swizzle (nwg = 1024, % 8 == 0)
  int nwg = gridDim.x;
  int wg  = blockIdx.x;
  int swz = (wg & 7) * (nwg >> 3) + (wg >> 3);
  int bm = (swz >> 4) << 8;
  int bn = (swz & 15) << 8;

  int tid = threadIdx.x;
  int wid = tid >> 6;
  int l   = tid & 63;
  int wm = wid >> 2, wn = wid & 3;

  // staging: lane covers global (row = base + wid*8 + (l>>3), slot = (l&7)^(row&7))
  int sg8 = ((l & 7) ^ ((l >> 3) & 7)) << 3;
  const ushort_t* pA = A  + (size_t)(bm + wid * 8 + (l >> 3)) * K_DIM + sg8;
  const ushort_t* pB = Bt + (size_t)(bn + wid * 8 + (l >> 3)) * K_DIM + sg8;
  ushort_t* sA0 = &lds[0][wid * 512];
  ushort_t* sA1 = &lds[1][wid * 512];
  ushort_t* sB0 = &lds[0][16384 + wid * 512];
  ushort_t* sB1 = &lds[1][16384 + wid * 512];

  // read bases: row = (wm*128 | mf*16 | (l&15)); slot = (ks*4 | (l>>4)) ^ (l&7)
  int slot0 = (l >> 4) ^ (l & 7);
  int aBase = (wm * 128 + (l & 15)) * 64 + slot0 * 8;
  int bBase = 16384 + (wn * 64 + (l & 15)) * 64 + slot0 * 8;

  f32x4 acc[8][4];
#pragma unroll
  for (int mf = 0; mf < 8; ++mf)
#pragma unroll
    for (int nf = 0; nf < 4; ++nf) acc[mf][nf] = (f32x4){0.f, 0.f, 0.f, 0.f};

  s16x8 a0f[4][2], a1f[4][2], b0[2][2], b1[2][2];

  // prologue: tile0 full (8 issues), tile1 B halves (4 issues); drain tile0
  STAGE_B(sB0, 0, 0); STAGE_B(sB0, 1, 0);
  STAGE_A(sA0, 0, 0); STAGE_A(sA0, 1, 0);
  STAGE_B(sB1, 0, 1); STAGE_B(sB1, 1, 1);
  VMW4; BAR;

  for (int j = 0; j < NTILE / 2 - 1; ++j) {   // j = 0..30, tiles 0..61
    int t1 = 2 * j + 1, t2 = 2 * j + 2, t3 = 2 * j + 3;
    // P1: read q0,n0,n1 (16); MFMA q00
    READ_A(0, a0f, 0); READ_B(0, b0, 0); READ_B(0, b1, 1);
    STAGE_A(sA1, 0, t1);
    BAR; MFMA_Q(a0f, b0, 0, 0); BAR;
    // P2: read q1 (8); MFMA q01 (overlaps q1 delivery)
    READ_A(0, a1f, 1);
    STAGE_A(sA1, 1, t1);
    BAR; MFMA_Q(a0f, b1, 0, 2); BAR;
    // P3: no reads; MFMA q11 (B(t2)->buf0 safe: all n-reads consumed by P2)
    STAGE_B(sB0, 0, t2);
    BAR; MFMA_Q(a1f, b1, 4, 2); BAR;
    // P4: no reads; MFMA q10; drain t1 (leaves P3,P4 in flight)
    STAGE_B(sB0, 1, t2);
    BAR; MFMA_Q(a1f, b0, 4, 0); VMW4; BAR;
    // P5
    READ_A(1, a0f, 0); READ_B(1, b0, 0); READ_B(1, b1, 1);
    STAGE_A(sA0, 0, t2);
    BAR; MFMA_Q(a0f, b0, 0, 0); BAR;
    // P6
    READ_A(1, a1f, 1);
    STAGE_A(sA0, 1, t2);
    BAR; MFMA_Q(a0f, b1, 0, 2); BAR;
    // P7
    STAGE_B(sB1, 0, t3);
    BAR; MFMA_Q(a1f, b1, 4, 2); BAR;
    // P8
    STAGE_B(sB1, 1, t3);
    BAR; MFMA_Q(a1f, b0, 4, 0); VMW4; BAR;
  }

  // tail: tiles 62 (buf0), 63 (buf1); t63 A still staged at P1,P2
  {
    READ_A(0, a0f, 0); READ_B(0, b0, 0); READ_B(0, b1, 1);
    STAGE_A(sA1, 0, 63);
    BAR; MFMA_Q(a0f, b0, 0, 0); BAR;

    READ_A(0, a1f, 1);
    STAGE_A(sA1, 1, 63);
    BAR; MFMA_Q(a0f, b1, 0, 2); BAR;

    BAR; MFMA_Q(a1f, b1, 4, 2); BAR;

    BAR; MFMA_Q(a1f, b0, 4, 0); VMW0; BAR;   // t63 A+B fully landed

    READ_A(1, a0f, 0); READ_B(1, b0, 0); READ_B(1, b1, 1);
    BAR; MFMA_Q(a0f, b0, 0, 0); BAR;

    READ_A(1, a1f, 1);
    BAR; MFMA_Q(a0f, b1, 0, 2); BAR;

    BAR; MFMA_Q(a1f, b1, 4, 2); BAR;

    BAR; MFMA_Q(a1f, b0, 4, 0);
  }

  // epilogue: C/D layout col = lane&15, row = (lane>>4)*4 + j
  int r0 = bm + wm * 128 + ((l >> 4) << 2);
  int c0 = bn + wn * 64 + (l & 15);
#pragma unroll
  for (int nf = 0; nf < 4; ++nf) {
    float bv = bias[c0 + nf * 16];
#pragma unroll
    for (int mf = 0; mf < 8; ++mf) {
#pragma unroll
      for (int jj = 0; jj < 4; ++jj)
        C[(size_t)(r0 + mf * 16 + jj) * N_DIM + (c0 + nf * 16)] = acc[mf][nf][jj] + bv;
    }
  }
}

// ---------- naive fp32 fallback (only if ws_size too small) ----------
__global__ __launch_bounds__(256)
void gemm_naive(const float* __restrict__ A, const float* __restrict__ B,
                const float* __restrict__ bias, float* __restrict__ C) {
  __shared__ float As[64][17];
  __shared__ float Bs[16][65];
  int nbn = N_DIM / 64;
  int m0 = (blockIdx.x / nbn) * 64;
  int n0 = (blockIdx.x % nbn) * 64;
  int tid = threadIdx.x;
  int tx = tid & 15, ty = tid >> 4;
  float acc[4][4] = {};
  for (int k0 = 0; k0 < K_DIM; k0 += 16) {
    __syncthreads();
#pragma unroll
    for (int e = tid * 4, i = 0; i < 4; ++i) {
      int idx = e + i;
      int r = idx >> 4, k = idx & 15;
      As[r][k] = A[(size_t)(m0 + r) * K_DIM + k0 + k];
    }
#pragma unroll
    for (int e = tid * 4, i = 0; i < 4; ++i) {
      int idx = e + i;
      int k = idx >> 6, n = idx & 63;
      Bs[k][n] = B[(size_t)(k0 + k) * N_DIM + n0 + n];
    }
    __syncthreads();
#pragma unroll
    for (int kk = 0; kk < 16; ++kk)
#pragma unroll
      for (int i = 0; i < 4; ++i)
#pragma unroll
        for (int j = 0; j < 4; ++j)
          acc[i][j] += As[ty * 4 + i][kk] * Bs[kk][tx * 4 + j];
  }
#pragma unroll
  for (int i = 0; i < 4; ++i)
#pragma unroll
    for (int j = 0; j < 4; ++j) {
      int r = m0 + ty * 4 + i, c = n0 + tx * 4 + j;
      C[(size_t)r * N_DIM + c] = acc[i][j] + bias[c];
    }
}

extern "C" void kernel_launch(void* const* d_in, const int* in_sizes, int n_in,
                              void* d_out, int out_size, void* d_ws, size_t ws_size,
                              hipStream_t stream) {
  const float* A32  = (const float*)d_in[0];
  const float* W32  = (const float*)d_in[1];
  const float* bias = (const float*)d_in[2];
  float* C = (float*)d_out;

  const size_t needA = (size_t)M_TOTAL * K_DIM * sizeof(ushort_t); // 128 MiB
  const size_t needB = (size_t)N_DIM * K_DIM * sizeof(ushort_t);   // 32 MiB

  if (ws_size >= needA + needB) {
    ushort_t* Abf = (ushort_t*)d_ws;
    ushort_t* Btb = (ushort_t*)((char*)d_ws + needA);
    long n8 = (long)M_TOTAL * K_DIM / 8;
    cast_kernel<<<(int)((n8 + 255) / 256), 256, 0, stream>>>(A32, Abf, n8);
    transpose_cast_kernel<<<(K_DIM / 64) * (N_DIM / 64), 256, 0, stream>>>(W32, Btb);
    gemm_8phase<<<(M_TOTAL / BM) * (N_DIM / BN), 512, 0, stream>>>(Abf, Btb, bias, C);
  } else {
    gemm_naive<<<(M_TOTAL / 64) * (N_DIM / 64), 256, 0, stream>>>(A32, W32, bias, C);
  }
}

// Round 6
// 554.054 us; speedup vs baseline: 1.2240x; 1.2240x over previous
//
#include <hip/hip_runtime.h>
#include <hip/hip_bf16.h>
#include <cstdint>
#include <cstddef>

#define M_TOTAL 16384   // WORLD_SIZE * M_LOCAL
#define K_DIM   4096
#define N_DIM   4096

typedef __attribute__((ext_vector_type(8))) short s16x8;
typedef __attribute__((ext_vector_type(4))) float f32x4;
typedef unsigned short ushort_t;

// ---------- fp32 -> bf16 round-to-nearest-even ----------
__device__ __forceinline__ ushort_t f2bf(float x) {
  unsigned u = __float_as_uint(x);
  return (ushort_t)((u + 0x7fffu + ((u >> 16) & 1u)) >> 16);
}

// ---------- cast A [M,K] fp32 -> bf16, 8 elems/thread ----------
__global__ __launch_bounds__(256) void cast_kernel(const float* __restrict__ in,
                                                   ushort_t* __restrict__ out,
                                                   long n8) {
  long i = (long)blockIdx.x * 256 + threadIdx.x;
  if (i >= n8) return;
  const f32x4* p = (const f32x4*)in + i * 2;
  f32x4 a = p[0], b = p[1];
  union { s16x8 v; ushort_t u[8]; } r;
  r.u[0] = f2bf(a.x); r.u[1] = f2bf(a.y); r.u[2] = f2bf(a.z); r.u[3] = f2bf(a.w);
  r.u[4] = f2bf(b.x); r.u[5] = f2bf(b.y); r.u[6] = f2bf(b.z); r.u[7] = f2bf(b.w);
  *((s16x8*)out + i) = r.v;
}

// ---------- transpose+cast W [K,N] fp32 -> Bt [N,K] bf16 ----------
__global__ __launch_bounds__(256) void transpose_cast_kernel(const float* __restrict__ B,
                                                             ushort_t* __restrict__ Bt) {
  __shared__ float tile[64][65];
  int nbx = N_DIM / 64;
  int n0 = (blockIdx.x % nbx) * 64;
  int k0 = (blockIdx.x / nbx) * 64;
  int tx = threadIdx.x & 63;
  int ty = threadIdx.x >> 6;
#pragma unroll
  for (int i = 0; i < 64; i += 4)
    tile[ty + i][tx] = B[(size_t)(k0 + ty + i) * N_DIM + n0 + tx];
  __syncthreads();
#pragma unroll
  for (int i = 0; i < 64; i += 4)
    Bt[(size_t)(n0 + ty + i) * K_DIM + k0 + tx] = f2bf(tile[tx][ty + i]);
}

// ============================================================================
// 256x256 8-phase bf16 GEMM — round 6: R3 base (487us, 0 conflicts, no spill)
// + WITHIN-PHASE READ SPLIT: half of each phase's ds_reads moved INSIDE the
// MFMA cluster (after the first 8 MFMAs), into the SAME registers the second
// 8 MFMAs consume -> LDS pipe serves group-2 reads while matrix pipe drains
// group 1. Register lifetimes/sets IDENTICAL to R3 (no extra pressure; R5's
// regression was spill from +32 live VGPRs at the 256/wave boundary).
// sched_group_barrier (MFMA 8 / DS_READ n / MFMA 8) pins the interleave;
// data deps force the right MFMA<->read grouping.
// Stage ledger / vmcnt / barriers / swizzle / epilogue IDENTICAL to R3.
// ============================================================================
#define BM 256
#define BN 256
#define BK 64
#define NTILE (K_DIM / BK)   // 64 -> 32 iterations, last peeled

__device__ __forceinline__ void load_lds16(const ushort_t* g, ushort_t* l) {
  __builtin_amdgcn_global_load_lds(
      (const __attribute__((address_space(1))) unsigned int*)g,
      (__attribute__((address_space(3))) unsigned int*)l, 16, 0, 0);
}

#define BAR __builtin_amdgcn_s_barrier()
#define VMW4 asm volatile("s_waitcnt vmcnt(4)" ::: "memory")
#define VMW0 asm volatile("s_waitcnt vmcnt(0)" ::: "memory")
#define PRIO1 __builtin_amdgcn_s_setprio(1)
#define PRIO0 __builtin_amdgcn_s_setprio(0)
// LLVM SchedGroupMask: MFMA=0x8, DS_READ=0x100
#define SGB_MFMA8 __builtin_amdgcn_sched_group_barrier(0x8, 8, 0)
#define SGB_DS(n) __builtin_amdgcn_sched_group_barrier(0x100, n, 0)

#define STAGE_A(dst, h, t) do { \
    load_lds16(pA + (size_t)((h) * 128) * K_DIM + (t) * 64, (dst) + (h) * 8192); \
    load_lds16(pA + (size_t)((h) * 128 + 64) * K_DIM + (t) * 64, (dst) + (h) * 8192 + 4096); } while (0)
#define STAGE_B(dst, h, t) do { \
    load_lds16(pB + (size_t)((h) * 128) * K_DIM + (t) * 64, (dst) + (h) * 8192); \
    load_lds16(pB + (size_t)((h) * 128 + 64) * K_DIM + (t) * 64, (dst) + (h) * 8192 + 4096); } while (0)

// 2 A-fragments (4 x b128): mf in {mf0, mf0+1} of quadrant q
#define READ_A2(buf, arr, q, mf0) do { \
    _Pragma("unroll") for (int mf = (mf0); mf < (mf0) + 2; ++mf) { \
      int ia = aBase + ((q) * 4 + mf) * 1024; \
      arr[mf][0] = *(const s16x8*)&lds[buf][ia]; \
      arr[mf][1] = *(const s16x8*)&lds[buf][ia ^ 32]; } } while (0)
// 1 B-fragment (2 x b128): single nf of n-half nh
#define READ_B1(buf, arr, nh, nf) do { \
    int ib = bBase + ((nh) * 2 + (nf)) * 1024; \
    arr[nf][0] = *(const s16x8*)&lds[buf][ib]; \
    arr[nf][1] = *(const s16x8*)&lds[buf][ib ^ 32]; } while (0)

// 8 MFMA: mf in {mf0,mf0+1} x nf{0,1} x ks{0,1}, ks outermost
#define MFMA_H_MF(arr_a, arr_b, m0, n0, mf0) do { \
    _Pragma("unroll") for (int ks = 0; ks < 2; ++ks) \
    _Pragma("unroll") for (int mf = (mf0); mf < (mf0) + 2; ++mf) \
    _Pragma("unroll") for (int nf = 0; nf < 2; ++nf) \
      acc[(m0) + mf][(n0) + nf] = __builtin_amdgcn_mfma_f32_16x16x32_bf16( \
          arr_a[mf][ks], arr_b[nf][ks], acc[(m0) + mf][(n0) + nf], 0, 0, 0); } while (0)
// 8 MFMA: mf 0..3 x single nf x ks{0,1}
#define MFMA_H_NF(arr_a, arr_b, m0, n0, nf) do { \
    _Pragma("unroll") for (int ks = 0; ks < 2; ++ks) \
    _Pragma("unroll") for (int mf = 0; mf < 4; ++mf) \
      acc[(m0) + mf][(n0) + (nf)] = __builtin_amdgcn_mfma_f32_16x16x32_bf16( \
          arr_a[mf][ks], arr_b[nf][ks], acc[(m0) + mf][(n0) + (nf)], 0, 0, 0); } while (0)

__global__ __launch_bounds__(512, 2)
void gemm_8phase(const ushort_t* __restrict__ A, const ushort_t* __restrict__ Bt,
                 const float* __restrict__ bias, float* __restrict__ C) {
  __shared__ ushort_t lds[2][32768];  // [buf][ A: 0..16383 | B: 16384..32767 ]

  // bijective XCD swizzle (nwg = 1024, % 8 == 0)
  int nwg = gridDim.x;
  int wg  = blockIdx.x;
  int swz = (wg & 7) * (nwg >> 3) + (wg >> 3);
  int bm = (swz >> 4) << 8;
  int bn = (swz & 15) << 8;

  int tid = threadIdx.x;
  int wid = tid >> 6;
  int l   = tid & 63;
  int wm = wid >> 2, wn = wid & 3;

  // staging: lane covers global (row = base + wid*8 + (l>>3), slot = (l&7)^(row&7))
  int sg8 = ((l & 7) ^ ((l >> 3) & 7)) << 3;
  const ushort_t* pA = A  + (size_t)(bm + wid * 8 + (l >> 3)) * K_DIM + sg8;
  const ushort_t* pB = Bt + (size_t)(bn + wid * 8 + (l >> 3)) * K_DIM + sg8;
  ushort_t* sA0 = &lds[0][wid * 512];
  ushort_t* sA1 = &lds[1][wid * 512];
  ushort_t* sB0 = &lds[0][16384 + wid * 512];
  ushort_t* sB1 = &lds[1][16384 + wid * 512];

  // read bases: row = (wm*128 | mf*16 | (l&15)); slot = (ks*4 | (l>>4)) ^ (l&7)
  int slot0 = (l >> 4) ^ (l & 7);
  int aBase = (wm * 128 + (l & 15)) * 64 + slot0 * 8;
  int bBase = 16384 + (wn * 64 + (l & 15)) * 64 + slot0 * 8;

  f32x4 acc[8][4];
#pragma unroll
  for (int mf = 0; mf < 8; ++mf)
#pragma unroll
    for (int nf = 0; nf < 4; ++nf) acc[mf][nf] = (f32x4){0.f, 0.f, 0.f, 0.f};

  s16x8 a[4][2], b0[2][2], b1[2][2];

  // prologue: tile0 full (8 issues), tile1 B halves (4 issues); drain tile0
  STAGE_B(sB0, 0, 0); STAGE_B(sB0, 1, 0);
  STAGE_A(sA0, 0, 0); STAGE_A(sA0, 1, 0);
  STAGE_B(sB1, 0, 1); STAGE_B(sB1, 1, 1);
  VMW4; BAR;

  for (int j = 0; j < NTILE / 2 - 1; ++j) {   // j = 0..30, tiles 0..61
    int t1 = 2 * j + 1, t2 = 2 * j + 2, t3 = 2 * j + 3;
    // P1: q00. pre: a-q0 mf01 + b0 (8 reads); mid: a-q0 mf23 (4)
    READ_A2(0, a, 0, 0); READ_B1(0, b0, 0, 0); READ_B1(0, b0, 0, 1);
    STAGE_A(sA1, 0, t1);
    BAR;
    PRIO1;
    MFMA_H_MF(a, b0, 0, 0, 0);
    READ_A2(0, a, 0, 2);
    MFMA_H_MF(a, b0, 0, 0, 2);
    PRIO0;
    SGB_MFMA8; SGB_DS(4); SGB_MFMA8;
    BAR;
    // P2: q01. pre: b1 nf0 (2); mid: b1 nf1 (2)
    READ_B1(0, b1, 1, 0);
    STAGE_A(sA1, 1, t1);
    BAR;
    PRIO1;
    MFMA_H_NF(a, b1, 0, 2, 0);
    READ_B1(0, b1, 1, 1);
    MFMA_H_NF(a, b1, 0, 2, 1);
    PRIO0;
    SGB_MFMA8; SGB_DS(2); SGB_MFMA8;
    BAR;
    // P3: q11. pre: a-q1 mf01 (4); mid: a-q1 mf23 (4)
    READ_A2(0, a, 1, 0);
    STAGE_B(sB0, 0, t2);
    BAR;
    PRIO1;
    MFMA_H_MF(a, b1, 4, 2, 0);
    READ_A2(0, a, 1, 2);
    MFMA_H_MF(a, b1, 4, 2, 2);
    PRIO0;
    SGB_MFMA8; SGB_DS(4); SGB_MFMA8;
    BAR;
    // P4: q10. no reads; drain t1 after cluster
    STAGE_B(sB0, 1, t2);
    BAR;
    PRIO1; MFMA_H_MF(a, b0, 4, 0, 0); MFMA_H_MF(a, b0, 4, 0, 2); PRIO0;
    VMW4;
    BAR;
    // P5: q00 (buf1)
    READ_A2(1, a, 0, 0); READ_B1(1, b0, 0, 0); READ_B1(1, b0, 0, 1);
    STAGE_A(sA0, 0, t2);
    BAR;
    PRIO1;
    MFMA_H_MF(a, b0, 0, 0, 0);
    READ_A2(1, a, 0, 2);
    MFMA_H_MF(a, b0, 0, 0, 2);
    PRIO0;
    SGB_MFMA8; SGB_DS(4); SGB_MFMA8;
    BAR;
    // P6: q01
    READ_B1(1, b1, 1, 0);
    STAGE_A(sA0, 1, t2);
    BAR;
    PRIO1;
    MFMA_H_NF(a, b1, 0, 2, 0);
    READ_B1(1, b1, 1, 1);
    MFMA_H_NF(a, b1, 0, 2, 1);
    PRIO0;
    SGB_MFMA8; SGB_DS(2); SGB_MFMA8;
    BAR;
    // P7: q11
    READ_A2(1, a, 1, 0);
    STAGE_B(sB1, 0, t3);
    BAR;
    PRIO1;
    MFMA_H_MF(a, b1, 4, 2, 0);
    READ_A2(1, a, 1, 2);
    MFMA_H_MF(a, b1, 4, 2, 2);
    PRIO0;
    SGB_MFMA8; SGB_DS(4); SGB_MFMA8;
    BAR;
    // P8: q10
    STAGE_B(sB1, 1, t3);
    BAR;
    PRIO1; MFMA_H_MF(a, b0, 4, 0, 0); MFMA_H_MF(a, b0, 4, 0, 2); PRIO0;
    VMW4;
    BAR;
  }

  // tail: tiles 62 (buf0), 63 (buf1); t63 A still staged at P1,P2 positions
  {
    READ_A2(0, a, 0, 0); READ_B1(0, b0, 0, 0); READ_B1(0, b0, 0, 1);
    STAGE_A(sA1, 0, 63);
    BAR;
    PRIO1;
    MFMA_H_MF(a, b0, 0, 0, 0);
    READ_A2(0, a, 0, 2);
    MFMA_H_MF(a, b0, 0, 0, 2);
    PRIO0;
    SGB_MFMA8; SGB_DS(4); SGB_MFMA8;
    BAR;

    READ_B1(0, b1, 1, 0);
    STAGE_A(sA1, 1, 63);
    BAR;
    PRIO1;
    MFMA_H_NF(a, b1, 0, 2, 0);
    READ_B1(0, b1, 1, 1);
    MFMA_H_NF(a, b1, 0, 2, 1);
    PRIO0;
    SGB_MFMA8; SGB_DS(2); SGB_MFMA8;
    BAR;

    READ_A2(0, a, 1, 0);
    BAR;
    PRIO1;
    MFMA_H_MF(a, b1, 4, 2, 0);
    READ_A2(0, a, 1, 2);
    MFMA_H_MF(a, b1, 4, 2, 2);
    PRIO0;
    SGB_MFMA8; SGB_DS(4); SGB_MFMA8;
    BAR;

    BAR;
    PRIO1; MFMA_H_MF(a, b0, 4, 0, 0); MFMA_H_MF(a, b0, 4, 0, 2); PRIO0;
    VMW0;   // t63 A+B fully landed
    BAR;

    READ_A2(1, a, 0, 0); READ_B1(1, b0, 0, 0); READ_B1(1, b0, 0, 1);
    BAR;
    PRIO1;
    MFMA_H_MF(a, b0, 0, 0, 0);
    READ_A2(1, a, 0, 2);
    MFMA_H_MF(a, b0, 0, 0, 2);
    PRIO0;
    SGB_MFMA8; SGB_DS(4); SGB_MFMA8;
    BAR;

    READ_B1(1, b1, 1, 0);
    BAR;
    PRIO1;
    MFMA_H_NF(a, b1, 0, 2, 0);
    READ_B1(1, b1, 1, 1);
    MFMA_H_NF(a, b1, 0, 2, 1);
    PRIO0;
    SGB_MFMA8; SGB_DS(2); SGB_MFMA8;
    BAR;

    READ_A2(1, a, 1, 0);
    BAR;
    PRIO1;
    MFMA_H_MF(a, b1, 4, 2, 0);
    READ_A2(1, a, 1, 2);
    MFMA_H_MF(a, b1, 4, 2, 2);
    PRIO0;
    SGB_MFMA8; SGB_DS(4); SGB_MFMA8;
    BAR;

    BAR;
    PRIO1; MFMA_H_MF(a, b0, 4, 0, 0); MFMA_H_MF(a, b0, 4, 0, 2); PRIO0;
  }

  // epilogue: C/D layout col = lane&15, row = (lane>>4)*4 + j
  int r0 = bm + wm * 128 + ((l >> 4) << 2);
  int c0 = bn + wn * 64 + (l & 15);
#pragma unroll
  for (int nf = 0; nf < 4; ++nf) {
    float bv = bias[c0 + nf * 16];
#pragma unroll
    for (int mf = 0; mf < 8; ++mf) {
#pragma unroll
      for (int jj = 0; jj < 4; ++jj)
        C[(size_t)(r0 + mf * 16 + jj) * N_DIM + (c0 + nf * 16)] = acc[mf][nf][jj] + bv;
    }
  }
}

// ---------- naive fp32 fallback (only if ws_size too small) ----------
__global__ __launch_bounds__(256)
void gemm_naive(const float* __restrict__ A, const float* __restrict__ B,
                const float* __restrict__ bias, float* __restrict__ C) {
  __shared__ float As[64][17];
  __shared__ float Bs[16][65];
  int nbn = N_DIM / 64;
  int m0 = (blockIdx.x / nbn) * 64;
  int n0 = (blockIdx.x % nbn) * 64;
  int tid = threadIdx.x;
  int tx = tid & 15, ty = tid >> 4;
  float acc[4][4] = {};
  for (int k0 = 0; k0 < K_DIM; k0 += 16) {
    __syncthreads();
#pragma unroll
    for (int e = tid * 4, i = 0; i < 4; ++i) {
      int idx = e + i;
      int r = idx >> 4, k = idx & 15;
      As[r][k] = A[(size_t)(m0 + r) * K_DIM + k0 + k];
    }
#pragma unroll
    for (int e = tid * 4, i = 0; i < 4; ++i) {
      int idx = e + i;
      int k = idx >> 6, n = idx & 63;
      Bs[k][n] = B[(size_t)(k0 + k) * N_DIM + n0 + n];
    }
    __syncthreads();
#pragma unroll
    for (int kk = 0; kk < 16; ++kk)
#pragma unroll
      for (int i = 0; i < 4; ++i)
#pragma unroll
        for (int j = 0; j < 4; ++j)
          acc[i][j] += As[ty * 4 + i][kk] * Bs[kk][tx * 4 + j];
  }
#pragma unroll
  for (int i = 0; i < 4; ++i)
#pragma unroll
    for (int j = 0; j < 4; ++j) {
      int r = m0 + ty * 4 + i, c = n0 + tx * 4 + j;
      C[(size_t)r * N_DIM + c] = acc[i][j] + bias[c];
    }
}

extern "C" void kernel_launch(void* const* d_in, const int* in_sizes, int n_in,
                              void* d_out, int out_size, void* d_ws, size_t ws_size,
                              hipStream_t stream) {
  const float* A32  = (const float*)d_in[0];
  const float* W32  = (const float*)d_in[1];
  const float* bias = (const float*)d_in[2];
  float* C = (float*)d_out;

  const size_t needA = (size_t)M_TOTAL * K_DIM * sizeof(ushort_t); // 128 MiB
  const size_t needB = (size_t)N_DIM * K_DIM * sizeof(ushort_t);   // 32 MiB

  if (ws_size >= needA + needB) {
    ushort_t* Abf = (ushort_t*)d_ws;
    ushort_t* Btb = (ushort_t*)((char*)d_ws + needA);
    long n8 = (long)M_TOTAL * K_DIM / 8;
    cast_kernel<<<(int)((n8 + 255) / 256), 256, 0, stream>>>(A32, Abf, n8);
    transpose_cast_kernel<<<(K_DIM / 64) * (N_DIM / 64), 256, 0, stream>>>(W32, Btb);
    gemm_8phase<<<(M_TOTAL / BM) * (N_DIM / BN), 512, 0, stream>>>(Abf, Btb, bias, C);
  } else {
    gemm_naive<<<(M_TOTAL / 64) * (N_DIM / 64), 256, 0, stream>>>(A32, W32, bias, C);
  }
}

// Round 7
// 541.342 us; speedup vs baseline: 1.2527x; 1.0235x over previous
//
#include <hip/hip_runtime.h>
#include <hip/hip_bf16.h>
#include <cstdint>
#include <cstddef>

#define M_TOTAL 16384   // WORLD_SIZE * M_LOCAL
#define K_DIM   4096
#define N_DIM   4096

typedef __attribute__((ext_vector_type(8))) short s16x8;
typedef __attribute__((ext_vector_type(4))) float f32x4;
typedef unsigned short ushort_t;

// ---------- fp32 -> bf16 round-to-nearest-even ----------
__device__ __forceinline__ ushort_t f2bf(float x) {
  unsigned u = __float_as_uint(x);
  return (ushort_t)((u + 0x7fffu + ((u >> 16) & 1u)) >> 16);
}

// ---------- cast A [M,K] fp32 -> bf16, 8 elems/thread ----------
__global__ __launch_bounds__(256) void cast_kernel(const float* __restrict__ in,
                                                   ushort_t* __restrict__ out,
                                                   long n8) {
  long i = (long)blockIdx.x * 256 + threadIdx.x;
  if (i >= n8) return;
  const f32x4* p = (const f32x4*)in + i * 2;
  f32x4 a = p[0], b = p[1];
  union { s16x8 v; ushort_t u[8]; } r;
  r.u[0] = f2bf(a.x); r.u[1] = f2bf(a.y); r.u[2] = f2bf(a.z); r.u[3] = f2bf(a.w);
  r.u[4] = f2bf(b.x); r.u[5] = f2bf(b.y); r.u[6] = f2bf(b.z); r.u[7] = f2bf(b.w);
  *((s16x8*)out + i) = r.v;
}

// ---------- transpose+cast W [K,N] fp32 -> Bt [N,K] bf16 ----------
__global__ __launch_bounds__(256) void transpose_cast_kernel(const float* __restrict__ B,
                                                             ushort_t* __restrict__ Bt) {
  __shared__ float tile[64][65];
  int nbx = N_DIM / 64;
  int n0 = (blockIdx.x % nbx) * 64;
  int k0 = (blockIdx.x / nbx) * 64;
  int tx = threadIdx.x & 63;
  int ty = threadIdx.x >> 6;
#pragma unroll
  for (int i = 0; i < 64; i += 4)
    tile[ty + i][tx] = B[(size_t)(k0 + ty + i) * N_DIM + n0 + tx];
  __syncthreads();
#pragma unroll
  for (int i = 0; i < 64; i += 4)
    Bt[(size_t)(n0 + ty + i) * K_DIM + k0 + tx] = f2bf(tile[tx][ty + i]);
}

// ============================================================================
// 256x256 bf16 GEMM — round 7: 4 MERGED PHASES / iter, SINGLE barrier / phase.
// R6 showed intra-phase placement is null; the 578cy/phase overhead is
// phase-boundary cost (16 barriers/iter + per-phase loop/sync overhead).
// Here: 4 phases x 32-MFMA clusters, ONE s_barrier per phase (after MFMA).
// Safety (no BAR before MFMA needed):
//   WAR: wave V's reads of region X complete (lgkmcnt) before V's MFMA,
//        which precedes V's arrival at BAR(p-1); wave W stages X only after
//        passing BAR(p-1) -> V's reads done before W's stage.  RAW: staged
//        data is drained by the OWNING wave's VMW4 before its BAR; readers
//        pass that BAR before reading.
// Ledger (iter j: t=2j in buf0 [PA1,PB1], t=2j+1 in buf1 [PA2,PB2]):
//   PA1: reads buf0 q0+b0+b1 (16 b128); stage A(2j+1)->buf1 (4 loads);
//        MFMA q00,q01 (32); BAR.
//   PB1: reads buf0 q1 (8); stage B(2j+2)->buf0 (4); MFMA q11,q10 (32);
//        VMW4 (outstanding A(t1)x4,B(t2)x4 -> leaves B(t2): A(t1) landed); BAR.
//   PA2: reads buf1 (16); stage A(2j+2)->buf0 (4); MFMA (32); BAR.
//   PB2: reads buf1 q1 (8); stage B(2j+3)->buf1 (4); MFMA (32);
//        VMW4 (leaves B(t3): B(t2),A(t2) landed); BAR.
// Register live-set identical to R3 (a[4][2], b0, b1) -> no spill (R5 lesson).
// ============================================================================
#define BM 256
#define BN 256
#define BK 64
#define NTILE (K_DIM / BK)   // 64 -> 32 iterations, last peeled

__device__ __forceinline__ void load_lds16(const ushort_t* g, ushort_t* l) {
  __builtin_amdgcn_global_load_lds(
      (const __attribute__((address_space(1))) unsigned int*)g,
      (__attribute__((address_space(3))) unsigned int*)l, 16, 0, 0);
}

#define BAR __builtin_amdgcn_s_barrier()
#define VMW4 asm volatile("s_waitcnt vmcnt(4)" ::: "memory")
#define VMW0 asm volatile("s_waitcnt vmcnt(0)" ::: "memory")
#define PRIO1 __builtin_amdgcn_s_setprio(1)
#define PRIO0 __builtin_amdgcn_s_setprio(0)

#define STAGE_A(dst, h, t) do { \
    load_lds16(pA + (size_t)((h) * 128) * K_DIM + (t) * 64, (dst) + (h) * 8192); \
    load_lds16(pA + (size_t)((h) * 128 + 64) * K_DIM + (t) * 64, (dst) + (h) * 8192 + 4096); } while (0)
#define STAGE_B(dst, h, t) do { \
    load_lds16(pB + (size_t)((h) * 128) * K_DIM + (t) * 64, (dst) + (h) * 8192); \
    load_lds16(pB + (size_t)((h) * 128 + 64) * K_DIM + (t) * 64, (dst) + (h) * 8192 + 4096); } while (0)

#define READ_A(buf, arr, q) do { \
    _Pragma("unroll") for (int mf = 0; mf < 4; ++mf) { \
      int ia = aBase + ((q) * 4 + mf) * 1024; \
      arr[mf][0] = *(const s16x8*)&lds[buf][ia]; \
      arr[mf][1] = *(const s16x8*)&lds[buf][ia ^ 32]; } } while (0)
#define READ_B(buf, arr, nh) do { \
    _Pragma("unroll") for (int nf = 0; nf < 2; ++nf) { \
      int ib = bBase + ((nh) * 2 + nf) * 1024; \
      arr[nf][0] = *(const s16x8*)&lds[buf][ib]; \
      arr[nf][1] = *(const s16x8*)&lds[buf][ib ^ 32]; } } while (0)

// 16 MFMA, ks outermost: 8 independent between accumulator reuse.
#define MFMA_Q(arr_a, arr_b, m0, n0) do { \
    _Pragma("unroll") for (int ks = 0; ks < 2; ++ks) \
    _Pragma("unroll") for (int mf = 0; mf < 4; ++mf) \
    _Pragma("unroll") for (int nf = 0; nf < 2; ++nf) \
      acc[(m0) + mf][(n0) + nf] = __builtin_amdgcn_mfma_f32_16x16x32_bf16( \
          arr_a[mf][ks], arr_b[nf][ks], acc[(m0) + mf][(n0) + nf], 0, 0, 0); } while (0)

__global__ __launch_bounds__(512, 2)
void gemm_4phase(const ushort_t* __restrict__ A, const ushort_t* __restrict__ Bt,
                 const float* __restrict__ bias, float* __restrict__ C) {
  __shared__ ushort_t lds[2][32768];  // [buf][ A: 0..16383 | B: 16384..32767 ]

  // bijective XCD swizzle (nwg = 1024, % 8 == 0)
  int nwg = gridDim.x;
  int wg  = blockIdx.x;
  int swz = (wg & 7) * (nwg >> 3) + (wg >> 3);
  int bm = (swz >> 4) << 8;
  int bn = (swz & 15) << 8;

  int tid = threadIdx.x;
  int wid = tid >> 6;
  int l   = tid & 63;
  int wm = wid >> 2, wn = wid & 3;

  // staging: lane covers global (row = base + wid*8 + (l>>3), slot = (l&7)^(row&7))
  int sg8 = ((l & 7) ^ ((l >> 3) & 7)) << 3;
  const ushort_t* pA = A  + (size_t)(bm + wid * 8 + (l >> 3)) * K_DIM + sg8;
  const ushort_t* pB = Bt + (size_t)(bn + wid * 8 + (l >> 3)) * K_DIM + sg8;
  ushort_t* sA0 = &lds[0][wid * 512];
  ushort_t* sA1 = &lds[1][wid * 512];
  ushort_t* sB0 = &lds[0][16384 + wid * 512];
  ushort_t* sB1 = &lds[1][16384 + wid * 512];

  // read bases: row = (wm*128 | mf*16 | (l&15)); slot = (ks*4 | (l>>4)) ^ (l&7)
  int slot0 = (l >> 4) ^ (l & 7);
  int aBase = (wm * 128 + (l & 15)) * 64 + slot0 * 8;
  int bBase = 16384 + (wn * 64 + (l & 15)) * 64 + slot0 * 8;

  f32x4 acc[8][4];
#pragma unroll
  for (int mf = 0; mf < 8; ++mf)
#pragma unroll
    for (int nf = 0; nf < 4; ++nf) acc[mf][nf] = (f32x4){0.f, 0.f, 0.f, 0.f};

  s16x8 a[4][2], b0[2][2], b1[2][2];

  // prologue: tile0 full (8 loads), tile1 B (4 loads); drain tile0 (leave B(t1))
  STAGE_B(sB0, 0, 0); STAGE_B(sB0, 1, 0);
  STAGE_A(sA0, 0, 0); STAGE_A(sA0, 1, 0);
  STAGE_B(sB1, 0, 1); STAGE_B(sB1, 1, 1);
  VMW4; BAR;

  for (int j = 0; j < NTILE / 2 - 1; ++j) {   // j = 0..30, tiles 0..61
    int t1 = 2 * j + 1, t2 = 2 * j + 2, t3 = 2 * j + 3;
    // PA1: tile 2j (buf0) q00+q01
    READ_A(0, a, 0); READ_B(0, b0, 0); READ_B(0, b1, 1);
    STAGE_A(sA1, 0, t1); STAGE_A(sA1, 1, t1);
    PRIO1; MFMA_Q(a, b0, 0, 0); MFMA_Q(a, b1, 0, 2); PRIO0;
    BAR;
    // PB1: tile 2j q11+q10; drain A(t1)
    READ_A(0, a, 1);
    STAGE_B(sB0, 0, t2); STAGE_B(sB0, 1, t2);
    PRIO1; MFMA_Q(a, b1, 4, 2); MFMA_Q(a, b0, 4, 0); PRIO0;
    VMW4; BAR;
    // PA2: tile 2j+1 (buf1) q00+q01
    READ_A(1, a, 0); READ_B(1, b0, 0); READ_B(1, b1, 1);
    STAGE_A(sA0, 0, t2); STAGE_A(sA0, 1, t2);
    PRIO1; MFMA_Q(a, b0, 0, 0); MFMA_Q(a, b1, 0, 2); PRIO0;
    BAR;
    // PB2: tile 2j+1 q11+q10; drain B(t2),A(t2)
    READ_A(1, a, 1);
    STAGE_B(sB1, 0, t3); STAGE_B(sB1, 1, t3);
    PRIO1; MFMA_Q(a, b1, 4, 2); MFMA_Q(a, b0, 4, 0); PRIO0;
    VMW4; BAR;
  }

  // tail: tiles 62 (buf0), 63 (buf1); B(63) staged in j=30's PB2
  {
    READ_A(0, a, 0); READ_B(0, b0, 0); READ_B(0, b1, 1);
    STAGE_A(sA1, 0, 63); STAGE_A(sA1, 1, 63);
    PRIO1; MFMA_Q(a, b0, 0, 0); MFMA_Q(a, b1, 0, 2); PRIO0;
    BAR;

    READ_A(0, a, 1);
    PRIO1; MFMA_Q(a, b1, 4, 2); MFMA_Q(a, b0, 4, 0); PRIO0;
    VMW0; BAR;   // drain A(63) (+ any residual B(63))

    READ_A(1, a, 0); READ_B(1, b0, 0); READ_B(1, b1, 1);
    PRIO1; MFMA_Q(a, b0, 0, 0); MFMA_Q(a, b1, 0, 2); PRIO0;
    BAR;

    READ_A(1, a, 1);
    PRIO1; MFMA_Q(a, b1, 4, 2); MFMA_Q(a, b0, 4, 0); PRIO0;
  }

  // epilogue: C/D layout col = lane&15, row = (lane>>4)*4 + j
  int r0 = bm + wm * 128 + ((l >> 4) << 2);
  int c0 = bn + wn * 64 + (l & 15);
#pragma unroll
  for (int nf = 0; nf < 4; ++nf) {
    float bv = bias[c0 + nf * 16];
#pragma unroll
    for (int mf = 0; mf < 8; ++mf) {
#pragma unroll
      for (int jj = 0; jj < 4; ++jj)
        C[(size_t)(r0 + mf * 16 + jj) * N_DIM + (c0 + nf * 16)] = acc[mf][nf][jj] + bv;
    }
  }
}

// ---------- naive fp32 fallback (only if ws_size too small) ----------
__global__ __launch_bounds__(256)
void gemm_naive(const float* __restrict__ A, const float* __restrict__ B,
                const float* __restrict__ bias, float* __restrict__ C) {
  __shared__ float As[64][17];
  __shared__ float Bs[16][65];
  int nbn = N_DIM / 64;
  int m0 = (blockIdx.x / nbn) * 64;
  int n0 = (blockIdx.x % nbn) * 64;
  int tid = threadIdx.x;
  int tx = tid & 15, ty = tid >> 4;
  float acc[4][4] = {};
  for (int k0 = 0; k0 < K_DIM; k0 += 16) {
    __syncthreads();
#pragma unroll
    for (int e = tid * 4, i = 0; i < 4; ++i) {
      int idx = e + i;
      int r = idx >> 4, k = idx & 15;
      As[r][k] = A[(size_t)(m0 + r) * K_DIM + k0 + k];
    }
#pragma unroll
    for (int e = tid * 4, i = 0; i < 4; ++i) {
      int idx = e + i;
      int k = idx >> 6, n = idx & 63;
      Bs[k][n] = B[(size_t)(k0 + k) * N_DIM + n0 + n];
    }
    __syncthreads();
#pragma unroll
    for (int kk = 0; kk < 16; ++kk)
#pragma unroll
      for (int i = 0; i < 4; ++i)
#pragma unroll
        for (int j = 0; j < 4; ++j)
          acc[i][j] += As[ty * 4 + i][kk] * Bs[kk][tx * 4 + j];
  }
#pragma unroll
  for (int i = 0; i < 4; ++i)
#pragma unroll
    for (int j = 0; j < 4; ++j) {
      int r = m0 + ty * 4 + i, c = n0 + tx * 4 + j;
      C[(size_t)r * N_DIM + c] = acc[i][j] + bias[c];
    }
}

extern "C" void kernel_launch(void* const* d_in, const int* in_sizes, int n_in,
                              void* d_out, int out_size, void* d_ws, size_t ws_size,
                              hipStream_t stream) {
  const float* A32  = (const float*)d_in[0];
  const float* W32  = (const float*)d_in[1];
  const float* bias = (const float*)d_in[2];
  float* C = (float*)d_out;

  const size_t needA = (size_t)M_TOTAL * K_DIM * sizeof(ushort_t); // 128 MiB
  const size_t needB = (size_t)N_DIM * K_DIM * sizeof(ushort_t);   // 32 MiB

  if (ws_size >= needA + needB) {
    ushort_t* Abf = (ushort_t*)d_ws;
    ushort_t* Btb = (ushort_t*)((char*)d_ws + needA);
    long n8 = (long)M_TOTAL * K_DIM / 8;
    cast_kernel<<<(int)((n8 + 255) / 256), 256, 0, stream>>>(A32, Abf, n8);
    transpose_cast_kernel<<<(K_DIM / 64) * (N_DIM / 64), 256, 0, stream>>>(W32, Btb);
    gemm_4phase<<<(M_TOTAL / BM) * (N_DIM / BN), 512, 0, stream>>>(Abf, Btb, bias, C);
  } else {
    gemm_naive<<<(M_TOTAL / 64) * (N_DIM / 64), 256, 0, stream>>>(A32, W32, bias, C);
  }
}